// Round 7
// baseline (149.960 us; speedup 1.0000x reference)
//
#include <hip/hip_runtime.h>

typedef short bf16x8 __attribute__((ext_vector_type(8)));   // 8 bf16 = 4 VGPRs
typedef float f32x16 __attribute__((ext_vector_type(16)));

// pack two fp32 into (bf16(b)<<16)|bf16(a) by truncation; paired with
// lo = x - trunc_bf16(x), the hi+lo split is exact to ~2^-17 rel.
__device__ __forceinline__ unsigned pack_hi(float a, float b) {
    return (__float_as_uint(b) & 0xffff0000u) | (__float_as_uint(a) >> 16);
}
__device__ __forceinline__ float lo_part(float v) {
    return v - __uint_as_float(__float_as_uint(v) & 0xffff0000u);
}

// tanh(a) given ap = 2*log2(e)*a:  tanh(a) = 1 - 2/(exp2(ap)+1)
__device__ __forceinline__ float tanh_fast(float ap) {
    float e = __builtin_amdgcn_exp2f(ap);
    return fmaf(-2.0f, __builtin_amdgcn_rcpf(e + 1.0f), 1.0f);
}

union FU { unsigned u[4]; bf16x8 v; };

// One wave = 32 batch elements (N-dim of mfma_f32_32x32x16_bf16).
// KEY IDENTITY (derived R7, implied by R6's pass): the C/D acc mapping
// (row=(r&3)+8(r>>2)+4H, col=n) and the B-operand mapping
// (k=(i&3)+8(i>>2)+4H, col=n) coincide with r=i+8c -- so the B-fragment for
// k-half c is simply acc regs i+8c OF THE SAME LANE. R6's LDS round-trip was
// an identity; deleted here (per-iter DS ops 120 -> 8 shfl_xor for fc2).
// 3-product split-bf16 (hi*hi + hi*lo + lo*hi; lo*lo dropped, <=1e-4 at y).
// Weight A-frags built in-register from raw weights once per wave.
__global__ __launch_bounds__(256, 2)
void rnn_mlp_kernel(const float* __restrict__ x,
                    const float* __restrict__ wih, const float* __restrict__ whh,
                    const float* __restrict__ bih, const float* __restrict__ bhh,
                    const float* __restrict__ w1,  const float* __restrict__ b1,
                    const float* __restrict__ w2,  const float* __restrict__ b2,
                    const float* __restrict__ w3,  const float* __restrict__ b3,
                    float* __restrict__ out, int B)
{
    const float K = 2.8853900817779268f; // 2*log2(e): tanh(a)=1-2/(exp2(K*a)+1)
    const int tid = threadIdx.x;
    const int wv = tid >> 6, l = tid & 63;
    const int n = l & 31, H = l >> 5;                     // n: acc col / A-row m; H: lane half

    // ---- one-time per-wave fragment build (from raw global weights) ----
    float WihS[16], CS[16];                               // rank-1 tables in C/D row layout
    #pragma unroll
    for (int r = 0; r < 16; ++r) {
        const int row = (r & 3) + 8 * (r >> 2) + 4 * H;
        WihS[r] = wih[row] * K;
        CS[r]   = (bih[row] + bhh[row]) * K;
    }
    FU whhF[2][2];                                        // [k-half c][hi/lo split]
    #pragma unroll
    for (int c = 0; c < 2; ++c)
        #pragma unroll
        for (int r = 0; r < 4; ++r) {
            const int j0 = c * 16 + 4 * H + 8 * (r >> 1) + 2 * (r & 1);
            const float a0 = whh[n * 32 + j0]     * K;
            const float a1 = whh[n * 32 + j0 + 1] * K;
            whhF[c][0].u[r] = pack_hi(a0, a1);
            whhF[c][1].u[r] = pack_hi(lo_part(a0), lo_part(a1));
        }
    FU w1F[3][2][2];                                      // [t][k-half c][split], rows m>=16 zero
    #pragma unroll
    for (int tt = 0; tt < 3; ++tt)
        #pragma unroll
        for (int c = 0; c < 2; ++c)
            #pragma unroll
            for (int r = 0; r < 4; ++r) {
                const int j0 = c * 16 + 4 * H + 8 * (r >> 1) + 2 * (r & 1);
                const float a0 = (n < 16) ? w1[n * 96 + tt * 32 + j0]     : 0.f;
                const float a1 = (n < 16) ? w1[n * 96 + tt * 32 + j0 + 1] : 0.f;
                w1F[tt][c][0].u[r] = pack_hi(a0, a1);
                w1F[tt][c][1].u[r] = pack_hi(lo_part(a0), lo_part(a1));
            }

    const int WSTRIDE = gridDim.x * 4 * 32;
    for (int base0 = (blockIdx.x * 4 + wv) * 32; base0 < B; base0 += WSTRIDE) {
        const int idx = base0 + n;
        const int ix  = (idx < B) ? idx : (B - 1);
        float xv[3];
        xv[0] = x[3*ix]; xv[1] = x[3*ix+1]; xv[2] = x[3*ix+2];

        f32x16 f1a, f1b;                                  // fc1 acc, two independent chains
        #pragma unroll
        for (int r = 0; r < 16; ++r) { f1a[r] = 0.f; f1b[r] = 0.f; }
        FU hF[2][2];

        #pragma unroll
        for (int t = 0; t < 3; ++t) {
            // pre-activation (K-scaled): rank-1 on VALU
            f32x16 av;
            #pragma unroll
            for (int r = 0; r < 16; ++r) av[r] = fmaf(xv[t], WihS[r], CS[r]);

            if (t > 0) {                                  // += K*Whh*h, 3-product split, 2 chains
                f32x16 av1;
                #pragma unroll
                for (int r = 0; r < 16; ++r) av1[r] = 0.f;
                av  = __builtin_amdgcn_mfma_f32_32x32x16_bf16(whhF[0][0].v, hF[0][0].v, av,  0,0,0);
                av  = __builtin_amdgcn_mfma_f32_32x32x16_bf16(whhF[0][0].v, hF[0][1].v, av,  0,0,0);
                av  = __builtin_amdgcn_mfma_f32_32x32x16_bf16(whhF[0][1].v, hF[0][0].v, av,  0,0,0);
                av1 = __builtin_amdgcn_mfma_f32_32x32x16_bf16(whhF[1][0].v, hF[1][0].v, av1, 0,0,0);
                av1 = __builtin_amdgcn_mfma_f32_32x32x16_bf16(whhF[1][0].v, hF[1][1].v, av1, 0,0,0);
                av1 = __builtin_amdgcn_mfma_f32_32x32x16_bf16(whhF[1][1].v, hF[1][0].v, av1, 0,0,0);
                #pragma unroll
                for (int r = 0; r < 16; ++r) av[r] += av1[r];
            }

            // tanh in-register; B-frag elem i of half c == value at reg i+8c (same lane)
            float h[16];
            #pragma unroll
            for (int r = 0; r < 16; ++r) h[r] = tanh_fast(av[r]);

            if (t < 2) {
                #pragma unroll
                for (int c = 0; c < 2; ++c)
                    #pragma unroll
                    for (int w = 0; w < 4; ++w) {
                        const float v0 = h[2*w + 8*c], v1 = h[2*w + 8*c + 1];
                        hF[c][0].u[w] = pack_hi(v0, v1);
                        hF[c][1].u[w] = pack_hi(lo_part(v0), lo_part(v1));
                    }
            }

            FU rF[2][2];
            #pragma unroll
            for (int c = 0; c < 2; ++c)
                #pragma unroll
                for (int w = 0; w < 4; ++w) {
                    const float r0 = fmaxf(h[2*w + 8*c],     0.f);
                    const float r1 = fmaxf(h[2*w + 8*c + 1], 0.f);
                    rF[c][0].u[w] = pack_hi(r0, r1);
                    rF[c][1].u[w] = pack_hi(lo_part(r0), lo_part(r1));
                }

            // fc1 += W1_t * relu(h): 3-product, two chains
            f1a = __builtin_amdgcn_mfma_f32_32x32x16_bf16(w1F[t][0][0].v, rF[0][0].v, f1a, 0,0,0);
            f1a = __builtin_amdgcn_mfma_f32_32x32x16_bf16(w1F[t][0][0].v, rF[0][1].v, f1a, 0,0,0);
            f1a = __builtin_amdgcn_mfma_f32_32x32x16_bf16(w1F[t][0][1].v, rF[0][0].v, f1a, 0,0,0);
            f1b = __builtin_amdgcn_mfma_f32_32x32x16_bf16(w1F[t][1][0].v, rF[1][0].v, f1b, 0,0,0);
            f1b = __builtin_amdgcn_mfma_f32_32x32x16_bf16(w1F[t][1][0].v, rF[1][1].v, f1b, 0,0,0);
            f1b = __builtin_amdgcn_mfma_f32_32x32x16_bf16(w1F[t][1][1].v, rF[1][0].v, f1b, 0,0,0);
        }

        // fc2/fc3. f1 rows live in acc regs 0..7: this lane holds rows
        // {0-3,8-11}+4H for col n; the other half's 8 rows come via shfl_xor(32).
        float f1s[8], o8[8];
        #pragma unroll
        for (int r = 0; r < 8; ++r) f1s[r] = f1a[r] + f1b[r];
        #pragma unroll
        for (int r = 0; r < 8; ++r) o8[r] = __shfl_xor(f1s[r], 32);
        // vA = rows {0-3,8-11}, vB = rows {4-7,12-15} (static indices; H-select)
        float vA[8], vB[8];
        #pragma unroll
        for (int r = 0; r < 8; ++r) {
            vA[r] = (H == 0) ? f1s[r] : o8[r];
            vB[r] = (H == 0) ? o8[r]  : f1s[r];
        }
        float g[8];
        #pragma unroll
        for (int o = 0; o < 8; ++o) g[o] = b2[o];
        #pragma unroll
        for (int r = 0; r < 8; ++r) {
            const int kA = (r & 3) + 8 * (r >> 2);        // rows 0-3, 8-11
            const int kB = kA + 4;                        // rows 4-7, 12-15
            const float va = vA[r] + b1[kA];
            const float vb = vB[r] + b1[kB];
            #pragma unroll
            for (int o = 0; o < 8; ++o) {
                g[o] = fmaf(va, w2[o*16 + kA], g[o]);
                g[o] = fmaf(vb, w2[o*16 + kB], g[o]);
            }
        }
        float y = b3[0];
        #pragma unroll
        for (int o = 0; o < 8; ++o) y = fmaf(fmaxf(g[o], 0.f), w3[o], y);
        if (H == 0 && idx < B) out[idx] = y;
    }
}

extern "C" void kernel_launch(void* const* d_in, const int* in_sizes, int n_in,
                              void* d_out, int out_size, void* d_ws, size_t ws_size,
                              hipStream_t stream)
{
    const float* x   = (const float*)d_in[0];
    const float* wih = (const float*)d_in[1];
    const float* whh = (const float*)d_in[2];
    const float* bih = (const float*)d_in[3];
    const float* bhh = (const float*)d_in[4];
    const float* w1  = (const float*)d_in[5];
    const float* b1  = (const float*)d_in[6];
    const float* w2  = (const float*)d_in[7];
    const float* b2  = (const float*)d_in[8];
    const float* w3  = (const float*)d_in[9];
    const float* b3  = (const float*)d_in[10];
    float* out = (float*)d_out;

    const int B = in_sizes[0] / 3;

    int blocks = (B + 127) / 128;                 // 4 waves/block, 32 elem/wave/iter
    if (blocks > 2048) blocks = 2048;             // grid-stride beyond this
    rnn_mlp_kernel<<<blocks, 256, 0, stream>>>(x, wih, whh, bih, bhh,
                                               w1, b1, w2, b2, w3, b3, out, B);
}

// Round 9
// 121.951 us; speedup vs baseline: 1.2297x; 1.2297x over previous
//
#include <hip/hip_runtime.h>

typedef _Float16 f16x8 __attribute__((ext_vector_type(8)));  // 8 f16 = 4 VGPRs
typedef __fp16  fp16x2 __attribute__((ext_vector_type(2)));  // pkrtz builtin's return type
typedef float f32x16 __attribute__((ext_vector_type(16)));

union FU { unsigned u[4]; f16x8 v; };

// v_cvt_pkrtz_f16_f32: two f32 -> packed 2xf16 (RTZ), ONE instruction.
// NOTE: the builtin returns __fp16-ext_vector, NOT _Float16-ext_vector (no
// implicit conversion -- R8's compile failure). Bit-copy through a union.
__device__ __forceinline__ unsigned pkrtz(float a, float b) {
    union { fp16x2 h; unsigned u; } c;
    c.h = __builtin_amdgcn_cvt_pkrtz(a, b);
    return c.u;
}
__device__ __forceinline__ float f16bits_to_f32(unsigned u16bits) {
    union { unsigned short s; _Float16 h; } c; c.s = (unsigned short)u16bits;
    return (float)c.h;
}

// tanh(a) given ap = 2*log2(e)*a:  tanh(a) = 1 - 2/(exp2(ap)+1)
__device__ __forceinline__ float tanh_fast(float ap) {
    float e = __builtin_amdgcn_exp2f(ap);
    return fmaf(-2.0f, __builtin_amdgcn_rcpf(e + 1.0f), 1.0f);
}

// One wave = 32 batch elements (N-dim of mfma_f32_32x32x16_f16).
// R7 post-mortem: VALU stream (not MFMA, not LDS) is the bound; the split-bf16
// pack glue was ~450 ops/iter. fp16 RTZ (2^-11) makes single-word activations
// accurate enough -> hF/rF build collapses to pkrtz ops. Whh kept exact via
// hi+lo f16 split (prologue-built, recurrent path); W1/W2 single f16.
// fc2 is ONE MFMA: f1-acc regs 0..7 row-set == B-operand k-set (same formula
// (i&3)+8(i>>2)+4H) -- the same layout identity that deleted the LDS stage.
// b1 folded: b2' = b2 + W2*b1. fc3 = 4 fma + shfl_xor(32).
__global__ __launch_bounds__(256, 2)
void rnn_mlp_kernel(const float* __restrict__ x,
                    const float* __restrict__ wih, const float* __restrict__ whh,
                    const float* __restrict__ bih, const float* __restrict__ bhh,
                    const float* __restrict__ w1,  const float* __restrict__ b1,
                    const float* __restrict__ w2,  const float* __restrict__ b2,
                    const float* __restrict__ w3,  const float* __restrict__ b3,
                    float* __restrict__ out, int B)
{
    const float K = 2.8853900817779268f; // 2*log2(e)
    const int tid = threadIdx.x;
    const int wv = tid >> 6, l = tid & 63;
    const int n = l & 31, H = l >> 5;                     // n: acc col / A-row m; H: lane half

    // ---- one-time per-wave fragment build ----
    float WihS[16], CS[16];                               // rank-1 tables, C/D row layout
    #pragma unroll
    for (int r = 0; r < 16; ++r) {
        const int row = (r & 3) + 8 * (r >> 2) + 4 * H;
        WihS[r] = wih[row] * K;
        CS[r]   = (bih[row] + bhh[row]) * K;
    }
    FU whhF[2][2];                                        // [k-half c][hi/lo split], exact Whh
    #pragma unroll
    for (int c = 0; c < 2; ++c)
        #pragma unroll
        for (int r = 0; r < 4; ++r) {
            const int j0 = c * 16 + 4 * H + 8 * (r >> 1) + 2 * (r & 1);
            const float a0 = whh[n * 32 + j0]     * K;
            const float a1 = whh[n * 32 + j0 + 1] * K;
            const unsigned hi = pkrtz(a0, a1);
            whhF[c][0].u[r] = hi;
            whhF[c][1].u[r] = pkrtz(a0 - f16bits_to_f32(hi & 0xffffu),
                                    a1 - f16bits_to_f32(hi >> 16));
        }
    FU w1F[3][2];                                         // [t][k-half c], single f16, rows>=16 zero
    #pragma unroll
    for (int tt = 0; tt < 3; ++tt)
        #pragma unroll
        for (int c = 0; c < 2; ++c)
            #pragma unroll
            for (int r = 0; r < 4; ++r) {
                const int j0 = c * 16 + 4 * H + 8 * (r >> 1) + 2 * (r & 1);
                const float a0 = (n < 16) ? w1[n * 96 + tt * 32 + j0]     : 0.f;
                const float a1 = (n < 16) ? w1[n * 96 + tt * 32 + j0 + 1] : 0.f;
                w1F[tt][c].u[r] = pkrtz(a0, a1);
            }
    FU w2F;                                               // fc2 A-frag (rows o>=8 zero), K=16
    #pragma unroll
    for (int r = 0; r < 4; ++r) {
        const int k0 = 4 * H + 8 * (r >> 1) + 2 * (r & 1);
        const float a0 = (n < 8) ? w2[n * 16 + k0]     : 0.f;
        const float a1 = (n < 8) ? w2[n * 16 + k0 + 1] : 0.f;
        w2F.u[r] = pkrtz(a0, a1);
    }
    float b2p[4], w3v[4];                                 // b2' = b2 + W2*b1 (b1 folded out)
    #pragma unroll
    for (int r = 0; r < 4; ++r) {
        const int o = r + 4 * H;
        float s = b2[o];
        #pragma unroll
        for (int k = 0; k < 16; ++k) s = fmaf(w2[o * 16 + k], b1[k], s);
        b2p[r] = s;
        w3v[r] = w3[o];
    }

    const int WSTRIDE = gridDim.x * 4 * 32;
    for (int base0 = (blockIdx.x * 4 + wv) * 32; base0 < B; base0 += WSTRIDE) {
        const int idx = base0 + n;
        const int ix  = (idx < B) ? idx : (B - 1);
        float xv[3];
        xv[0] = x[3*ix]; xv[1] = x[3*ix+1]; xv[2] = x[3*ix+2];

        f32x16 f1a, f1b;                                  // fc1 acc, two chains
        #pragma unroll
        for (int r = 0; r < 16; ++r) { f1a[r] = 0.f; f1b[r] = 0.f; }
        FU hF[2];

        #pragma unroll
        for (int t = 0; t < 3; ++t) {
            // pre-activation (K-scaled) rank-1 on VALU, then matvec MFMAs chained on av
            f32x16 av;
            #pragma unroll
            for (int r = 0; r < 16; ++r) av[r] = fmaf(xv[t], WihS[r], CS[r]);
            if (t > 0) {
                av = __builtin_amdgcn_mfma_f32_32x32x16_f16(whhF[0][0].v, hF[0].v, av, 0,0,0);
                av = __builtin_amdgcn_mfma_f32_32x32x16_f16(whhF[0][1].v, hF[0].v, av, 0,0,0);
                av = __builtin_amdgcn_mfma_f32_32x32x16_f16(whhF[1][0].v, hF[1].v, av, 0,0,0);
                av = __builtin_amdgcn_mfma_f32_32x32x16_f16(whhF[1][1].v, hF[1].v, av, 0,0,0);
            }

            float h[16];
            #pragma unroll
            for (int r = 0; r < 16; ++r) h[r] = tanh_fast(av[r]);

            // B-frag elem i of half c == value at reg i+8c (same-lane identity)
            FU rF[2];
            #pragma unroll
            for (int c = 0; c < 2; ++c)
                #pragma unroll
                for (int w = 0; w < 4; ++w) {
                    const float v0 = h[2*w + 8*c], v1 = h[2*w + 8*c + 1];
                    if (t < 2) hF[c].u[w] = pkrtz(v0, v1);
                    rF[c].u[w] = pkrtz(fmaxf(v0, 0.f), fmaxf(v1, 0.f));
                }

            f1a = __builtin_amdgcn_mfma_f32_32x32x16_f16(w1F[t][0].v, rF[0].v, f1a, 0,0,0);
            f1b = __builtin_amdgcn_mfma_f32_32x32x16_f16(w1F[t][1].v, rF[1].v, f1b, 0,0,0);
        }

        // fc2 via ONE MFMA (f1 regs 0..7 == B-frag k-layout), then fc3 on VALU
        FU bB;
        #pragma unroll
        for (int w = 0; w < 4; ++w)
            bB.u[w] = pkrtz(f1a[2*w] + f1b[2*w], f1a[2*w+1] + f1b[2*w+1]);
        f32x16 gacc;
        #pragma unroll
        for (int r = 0; r < 16; ++r) gacc[r] = 0.f;
        gacc = __builtin_amdgcn_mfma_f32_32x32x16_f16(w2F.v, bB.v, gacc, 0,0,0);

        float p = 0.f;
        #pragma unroll
        for (int r = 0; r < 4; ++r)                       // lane holds g rows r+4H
            p = fmaf(fmaxf(gacc[r] + b2p[r], 0.f), w3v[r], p);
        const float y = p + __shfl_xor(p, 32) + b3[0];
        if (H == 0 && idx < B) out[idx] = y;
    }
}

extern "C" void kernel_launch(void* const* d_in, const int* in_sizes, int n_in,
                              void* d_out, int out_size, void* d_ws, size_t ws_size,
                              hipStream_t stream)
{
    const float* x   = (const float*)d_in[0];
    const float* wih = (const float*)d_in[1];
    const float* whh = (const float*)d_in[2];
    const float* bih = (const float*)d_in[3];
    const float* bhh = (const float*)d_in[4];
    const float* w1  = (const float*)d_in[5];
    const float* b1  = (const float*)d_in[6];
    const float* w2  = (const float*)d_in[7];
    const float* b2  = (const float*)d_in[8];
    const float* w3  = (const float*)d_in[9];
    const float* b3  = (const float*)d_in[10];
    float* out = (float*)d_out;

    const int B = in_sizes[0] / 3;

    int blocks = (B + 127) / 128;                 // 4 waves/block, 32 elem/wave/iter
    if (blocks > 2048) blocks = 2048;             // grid-stride beyond this
    rnn_mlp_kernel<<<blocks, 256, 0, stream>>>(x, wih, whh, bih, bhh,
                                               w1, b1, w2, b2, w3, b3, out, B);
}